// Round 11
// baseline (69.574 us; speedup 1.0000x reference)
//
#include <hip/hip_runtime.h>
#include <cstring>
#include <cstdint>
#include <cmath>

typedef __fp16 half2v __attribute__((ext_vector_type(2)));

// ---------------------------------------------------------------------------
// Threefry-2x32 (20 rounds) — exact JAX PRNG
// ---------------------------------------------------------------------------
__host__ __device__ static inline uint32_t rotl32(uint32_t v, int r) {
    return __builtin_rotateleft32(v, (unsigned)r);
}

__host__ __device__ static inline void tf2x32(uint32_t k0, uint32_t k1,
                                              uint32_t& x0, uint32_t& x1) {
    uint32_t ks2 = k0 ^ k1 ^ 0x1BD11BDAu;
    x0 += k0; x1 += k1;
#define TFR(r) { x0 += x1; x1 = rotl32(x1, r); x1 ^= x0; }
    TFR(13) TFR(15) TFR(26) TFR(6)
    x0 += k1;  x1 += ks2 + 1u;
    TFR(17) TFR(29) TFR(16) TFR(24)
    x0 += ks2; x1 += k0 + 2u;
    TFR(13) TFR(15) TFR(26) TFR(6)
    x0 += k0;  x1 += k1 + 3u;
    TFR(17) TFR(29) TFR(16) TFR(24)
    x0 += k1;  x1 += ks2 + 4u;
    TFR(13) TFR(15) TFR(26) TFR(6)
    x0 += ks2; x1 += k0 + 5u;
#undef TFR
}

// Partitionable-mode 32-bit random bits for flat index i: counter (0,i); out0^out1
__host__ __device__ static inline uint32_t pbits(uint32_t k0, uint32_t k1, uint32_t i) {
    uint32_t a = 0u, b = i;
    tf2x32(k0, k1, a, b);
    return a ^ b;
}

// bits -> uniform [0,1) exactly as jax
__host__ __device__ static inline float bits_to_u01(uint32_t bits) {
    uint32_t u = (bits >> 9) | 0x3f800000u;
    float f; memcpy(&f, &u, 4);
    return f - 1.0f;
}

// XLA ErfInv (Giles 2010, float32) — PRECISE version (host-side params only)
__host__ static inline float erfinv_f(float x) {
    float w = -log1pf(-x * x);
    float p;
    if (w < 5.0f) {
        w = w - 2.5f;
        p = 2.81022636e-08f;
        p = fmaf(p, w, 3.43273939e-07f);
        p = fmaf(p, w, -3.5233877e-06f);
        p = fmaf(p, w, -4.39150654e-06f);
        p = fmaf(p, w, 0.00021858087f);
        p = fmaf(p, w, -0.00125372503f);
        p = fmaf(p, w, -0.00417768164f);
        p = fmaf(p, w, 0.246640727f);
        p = fmaf(p, w, 1.50140941f);
    } else {
        w = sqrtf(w) - 3.0f;
        p = -0.000200214257f;
        p = fmaf(p, w, 0.000100950558f);
        p = fmaf(p, w, 0.00134934322f);
        p = fmaf(p, w, -0.00367342844f);
        p = fmaf(p, w, 0.00573950773f);
        p = fmaf(p, w, -0.0076224613f);
        p = fmaf(p, w, 0.00943887047f);
        p = fmaf(p, w, 1.00167406f);
        p = fmaf(p, w, 2.83297682f);
    }
    return p * x;
}

__host__ static inline float normal_from_bits(uint32_t bits) {
    const float LO = -0.999999940395355224609375f;  // -1 + 2^-24
    float u01 = bits_to_u01(bits);
    float u = u01 * 2.0f + LO;
    u = (u > LO) ? u : LO;
    return 1.4142135623730951f * erfinv_f(u);
}

// ---------------------------------------------------------------------------
// Device-fast normal (validated rounds 3-9: absmax stable 0.0625)
// ---------------------------------------------------------------------------
__device__ __forceinline__ float normal_fast(uint32_t bits) {
    const float LO = -0.999999940395355224609375f;
    uint32_t u = (bits >> 9) | 0x3f800000u;
    float x = fmaf(__uint_as_float(u) - 1.0f, 2.0f, LO);
    x = fmaxf(x, LO);
    float t = fmaf(x, -x, 1.0f);            // 1 - x^2, single rounding
    float lg = __log2f(t);                   // v_log_f32
    float p;
    if (__builtin_expect(lg > -7.2134752044448170f, 1)) {   // w < 5
        float w = fmaf(lg, -0.6931471805599453f, -2.5f);
        p = 2.81022636e-08f;
        p = fmaf(p, w, 3.43273939e-07f);
        p = fmaf(p, w, -3.5233877e-06f);
        p = fmaf(p, w, -4.39150654e-06f);
        p = fmaf(p, w, 0.00021858087f);
        p = fmaf(p, w, -0.00125372503f);
        p = fmaf(p, w, -0.00417768164f);
        p = fmaf(p, w, 0.246640727f);
        p = fmaf(p, w, 1.50140941f);
    } else {
        float w = sqrtf(lg * -0.6931471805599453f) - 3.0f;
        p = -0.000200214257f;
        p = fmaf(p, w, 0.000100950558f);
        p = fmaf(p, w, 0.00134934322f);
        p = fmaf(p, w, -0.00367342844f);
        p = fmaf(p, w, 0.00573950773f);
        p = fmaf(p, w, -0.0076224613f);
        p = fmaf(p, w, 0.00943887047f);
        p = fmaf(p, w, 1.00167406f);
        p = fmaf(p, w, 2.83297682f);
    }
    return 1.4142135623730951f * p * x;
}

// Three interleaved threefry chains (same key, counters l, l+256K, l+512K).
__device__ __forceinline__ void noise3(uint32_t k0, uint32_t k1, uint32_t l,
                                       float& n0, float& n1, float& n2) {
    const uint32_t ks2 = k0 ^ k1 ^ 0x1BD11BDAu;
    uint32_t a0 = k0, b0 = l + k1;
    uint32_t a1 = k0, b1 = (l + 262144u) + k1;
    uint32_t a2 = k0, b2 = (l + 524288u) + k1;
#define R3(r)      { a0 += b0; b0 = rotl32(b0, r); b0 ^= a0; \
                     a1 += b1; b1 = rotl32(b1, r); b1 ^= a1; \
                     a2 += b2; b2 = rotl32(b2, r); b2 ^= a2; }
#define INJ(ka,kb) { a0 += (ka); b0 += (kb); a1 += (ka); b1 += (kb); a2 += (ka); b2 += (kb); }
    R3(13) R3(15) R3(26) R3(6)  INJ(k1,  ks2 + 1u)
    R3(17) R3(29) R3(16) R3(24) INJ(ks2, k0  + 2u)
    R3(13) R3(15) R3(26) R3(6)  INJ(k0,  k1  + 3u)
    R3(17) R3(29) R3(16) R3(24) INJ(k1,  ks2 + 4u)
    R3(13) R3(15) R3(26) R3(6)  INJ(ks2, k0  + 5u)
#undef R3
#undef INJ
    n0 = normal_fast(a0 ^ b0);
    n1 = normal_fast(a1 ^ b1);
    n2 = normal_fast(a2 ^ b2);
}

// ---------------------------------------------------------------------------
// Host-side float32 4x4 matrix helpers (exact reference mirror)
// ---------------------------------------------------------------------------
struct M4 { float m[4][4]; };

static M4 m4_eye() {
    M4 r;
    for (int i = 0; i < 4; ++i)
        for (int j = 0; j < 4; ++j) r.m[i][j] = (i == j) ? 1.0f : 0.0f;
    return r;
}
static M4 m4_mul(const M4& A, const M4& B) {
    M4 r;
    for (int i = 0; i < 4; ++i)
        for (int j = 0; j < 4; ++j) {
            float s = 0.0f;
            for (int k = 0; k < 4; ++k) s += A.m[i][k] * B.m[k][j];
            r.m[i][j] = s;
        }
    return r;
}
static M4 m4_scale(float sx, float sy, float sz) {
    M4 r = m4_eye(); r.m[0][0] = sx; r.m[1][1] = sy; r.m[2][2] = sz; return r;
}
static M4 m4_trans(float tx, float ty, float tz) {
    M4 r = m4_eye(); r.m[0][3] = tx; r.m[1][3] = ty; r.m[2][3] = tz; return r;
}
static M4 m4_rotz(float th) {
    float c = cosf(th), s = sinf(th);
    M4 r = m4_eye();
    r.m[0][0] = c; r.m[0][1] = -s; r.m[1][0] = s; r.m[1][1] = c;
    return r;
}
static M4 m4_rotluma(float th) {
    const float a  = 0.57735026918962576f;
    const float a2 = 1.0f / 3.0f;
    float c = cosf(th), s = sinf(th), cc = 1.0f - c;
    float d  = a2 * cc + c;
    float mm = a2 * cc - a * s;
    float pp = a2 * cc + a * s;
    M4 r = m4_eye();
    r.m[0][0] = d;  r.m[0][1] = mm; r.m[0][2] = pp;
    r.m[1][0] = pp; r.m[1][1] = d;  r.m[1][2] = mm;
    r.m[2][0] = mm; r.m[2][1] = pp; r.m[2][2] = d;
    return r;
}

// ---------------------------------------------------------------------------
struct AugParams {
    float G[16][12];
    float C[16][12];
    float sigma[16];
    float cx[16], cy[16], cz[16];
    uint32_t nk0, nk1;
};

static void build_params(AugParams& P) {
    uint32_t sk0[24], sk1[24];
    for (int j = 0; j < 24; ++j) {
        uint32_t a = 0u, b = (uint32_t)j;
        tf2x32(0u, 42u, a, b);
        sk0[j] = a; sk1[j] = b;
    }

    float u_xf[16], u_r90[16], u_ti[48], n_sc[16], u_r1[16], n_an[16], u_r2[16];
    float n_tf[48], n_br[16], n_ct[16], u_lf[16], u_hue[16], n_sat[16], n_sig[16], u_cut[48];

    auto fill_u = [&](int j, int n, float* o) {
        for (int i = 0; i < n; ++i) o[i] = bits_to_u01(pbits(sk0[j], sk1[j], (uint32_t)i));
    };
    auto fill_n = [&](int j, int n, float* o) {
        for (int i = 0; i < n; ++i) o[i] = normal_from_bits(pbits(sk0[j], sk1[j], (uint32_t)i));
    };

    fill_u(0, 16, u_xf);  fill_u(1, 16, u_r90);  fill_u(2, 48, u_ti);
    fill_n(3, 16, n_sc);  fill_u(4, 16, u_r1);   fill_n(5, 16, n_an);
    fill_u(6, 16, u_r2);  fill_n(7, 48, n_tf);   fill_n(8, 16, n_br);
    fill_n(9, 16, n_ct);  fill_u(10, 16, u_lf);  fill_u(11, 16, u_hue);
    fill_n(12, 16, n_sat); fill_n(13, 16, n_sig); fill_u(15, 48, u_cut);
    P.nk0 = sk0[14]; P.nk1 = sk1[14];

    const float PI_F = 3.14159265358979323846f;
    const float HPI_F = 1.5707963267948966f;

    for (int b = 0; b < 16; ++b) {
        M4 G = m4_eye();
        float i1 = floorf(u_xf[b] * 2.0f);
        G = m4_mul(G, m4_scale(1.0f - 2.0f * i1, 1.0f, 1.0f));
        float i2 = floorf(u_r90[b] * 4.0f);
        G = m4_mul(G, m4_rotz(-HPI_F * i2));
        float t0 = (u_ti[3 * b + 0] * 2.0f - 1.0f) * 0.125f;
        float t1 = (u_ti[3 * b + 1] * 2.0f - 1.0f) * 0.125f;
        float t2 = (u_ti[3 * b + 2] * 2.0f - 1.0f) * 0.125f;
        G = m4_mul(G, m4_trans(-rintf(t0 * 64.0f), -rintf(t1 * 64.0f), -rintf(t2 * 64.0f)));
        float s = exp2f(n_sc[b] * 0.2f);
        G = m4_mul(G, m4_scale(1.0f / s, 1.0f / s, 1.0f / s));
        float th1 = (u_r1[b] * 2.0f - 1.0f) * PI_F;
        G = m4_mul(G, m4_rotz(-th1));
        float s2 = exp2f(n_an[b] * 0.2f);
        G = m4_mul(G, m4_scale(1.0f / s2, s2, 1.0f));
        float th2 = (u_r2[b] * 2.0f - 1.0f) * PI_F;
        G = m4_mul(G, m4_rotz(-th2));
        float f0 = n_tf[3 * b + 0] * 0.125f;
        float f1 = n_tf[3 * b + 1] * 0.125f;
        float f2 = n_tf[3 * b + 2] * 0.125f;
        G = m4_mul(G, m4_trans(-f0 * 64.0f, -f1 * 64.0f, -f2 * 64.0f));

        M4 C = m4_eye();
        float br = n_br[b] * 0.2f;
        C = m4_mul(m4_trans(br, br, br), C);
        float ct = exp2f(n_ct[b] * 0.5f);
        C = m4_mul(m4_scale(ct, ct, ct), C);
        const float va = 0.57735026918962576f;
        float v4[4] = { va, va, va, 0.0f };
        float ilf = floorf(u_lf[b] * 2.0f);
        M4 L;
        for (int r = 0; r < 4; ++r)
            for (int c = 0; c < 4; ++c)
                L.m[r][c] = ((r == c) ? 1.0f : 0.0f) - 2.0f * (v4[r] * v4[c]) * ilf;
        C = m4_mul(L, C);
        float thh = (u_hue[b] * 2.0f - 1.0f) * PI_F;
        C = m4_mul(m4_rotluma(thh), C);
        float ss = exp2f(n_sat[b] * 1.0f);
        M4 S;
        for (int r = 0; r < 4; ++r)
            for (int c = 0; c < 4; ++c) {
                float vv = v4[r] * v4[c];
                S.m[r][c] = vv + (((r == c) ? 1.0f : 0.0f) - vv) * ss;
            }
        C = m4_mul(S, C);

        P.sigma[b] = fabsf(n_sig[b]) * 0.1f;
        P.cx[b] = u_cut[3 * b + 0];
        P.cy[b] = u_cut[3 * b + 1];
        P.cz[b] = u_cut[3 * b + 2];
        for (int r = 0; r < 3; ++r)
            for (int c = 0; c < 4; ++c) {
                P.G[b][r * 4 + c] = G.m[r][c];
                P.C[b][r * 4 + c] = C.m[r][c];
            }
    }
}

// ---------------------------------------------------------------------------
// Kernel 1: repack planar->RGBA float4 AND compute the 3 noise normals
// (threefry+erfinv hides under the memory traffic), f16-packed into uint2.
// ---------------------------------------------------------------------------
__global__ __launch_bounds__(256) void repack_noise_kernel(const float* __restrict__ in,
                                                           float4* __restrict__ ws4,
                                                           uint2* __restrict__ nz,
                                                           uint32_t nk0, uint32_t nk1) {
    const int t = blockIdx.x * 256 + threadIdx.x;      // 0 .. 4194303
    const int b = t >> 18;
    const int vox = t & 262143;
    const float* p = in + (size_t)b * 786432 + vox;
    float4 q;
    q.x = p[0];
    q.y = p[262144];
    q.z = p[524288];
    q.w = 0.0f;

    // RNG for this voxel's 3 channels (VALU hides under load/store latency)
    const uint32_t l0 = (uint32_t)b * 786432u + (uint32_t)vox;
    float n0, n1, n2;
    noise3(nk0, nk1, l0, n0, n1, n2);
    half2v p01 = __builtin_amdgcn_cvt_pkrtz(n0, n1);   // v_cvt_pkrtz_f16_f32
    half2v p2x = __builtin_amdgcn_cvt_pkrtz(n2, 0.0f);
    uint2 nv;
    memcpy(&nv.x, &p01, 4);
    memcpy(&nv.y, &p2x, 4);

    ws4[t] = q;
    nz[t] = nv;
}

// ---------------------------------------------------------------------------
// Kernel 2: main fused augment — float4 corner gathers + precomputed noise.
// ---------------------------------------------------------------------------
__global__ __launch_bounds__(256, 4) void aug_kernel4n(const float4* __restrict__ ws4,
                                                       const uint2* __restrict__ nz,
                                                       float* __restrict__ out,
                                                       AugParams P) {
    const int bid = blockIdx.x;
    const int b = bid >> 10;                              // 1024 blocks per batch
    const int vox = ((bid & 1023) << 8) | threadIdx.x;    // 0..262143
    const int x = vox & 63;
    const int y = (vox >> 6) & 63;
    const int z = vox >> 12;

    const float* Gb = P.G[b];
    const float hx = (float)x - 31.5f;
    const float hy = (float)y - 31.5f;
    const float hz = (float)z - 31.5f;
    float sx = Gb[0] * hx + Gb[1] * hy + Gb[2]  * hz + Gb[3]  + 31.5f;
    float sy = Gb[4] * hx + Gb[5] * hy + Gb[6]  * hz + Gb[7]  + 31.5f;
    float sz = Gb[8] * hx + Gb[9] * hy + Gb[10] * hz + Gb[11] + 31.5f;

    float fx = floorf(sx), fy = floorf(sy), fz = floorf(sz);
    float wx = sx - fx, wy = sy - fy, wz = sz - fz;
    int ix = (int)fx, iy = (int)fy, iz = (int)fz;

    float xw0 = ((unsigned)ix       < 64u) ? 1.0f - wx : 0.0f;
    float xw1 = ((unsigned)(ix + 1) < 64u) ? wx        : 0.0f;
    float yw0 = ((unsigned)iy       < 64u) ? 1.0f - wy : 0.0f;
    float yw1 = ((unsigned)(iy + 1) < 64u) ? wy        : 0.0f;
    float zw0 = ((unsigned)iz       < 64u) ? 1.0f - wz : 0.0f;
    float zw1 = ((unsigned)(iz + 1) < 64u) ? wz        : 0.0f;

    int xc0 = min(max(ix, 0), 63),       xc1 = min(max(ix + 1, 0), 63);
    int yo0 = min(max(iy, 0), 63) << 6,  yo1 = min(max(iy + 1, 0), 63) << 6;
    int zo0 = min(max(iz, 0), 63) << 12, zo1 = min(max(iz + 1, 0), 63) << 12;

    float w00 = zw0 * yw0, w01 = zw0 * yw1, w10 = zw1 * yw0, w11 = zw1 * yw1;
    int   o00 = zo0 + yo0, o01 = zo0 + yo1, o10 = zo1 + yo0, o11 = zo1 + yo1;

    const float4* __restrict__ w4 = ws4 + (size_t)b * 262144;
    // noise load early (coalesced 8B)
    uint2 nv = nz[(size_t)b * 262144 + vox];

    float r = 0.0f, g = 0.0f, bl = 0.0f;
#define CORNER4(W, O) { \
    float4 qa = w4[(O) + xc0]; float4 qb = w4[(O) + xc1]; \
    const float wg0 = (W) * xw0, wg1 = (W) * xw1; \
    r  = fmaf(qa.x, wg0, r);  r  = fmaf(qb.x, wg1, r);  \
    g  = fmaf(qa.y, wg0, g);  g  = fmaf(qb.y, wg1, g);  \
    bl = fmaf(qa.z, wg0, bl); bl = fmaf(qb.z, wg1, bl); }
    CORNER4(w00, o00) CORNER4(w01, o01) CORNER4(w10, o10) CORNER4(w11, o11)
#undef CORNER4

    // decode noise (f16 -> f32)
    half2v p01, p2x;
    memcpy(&p01, &nv.x, 4);
    memcpy(&p2x, &nv.y, 4);
    float n0 = (float)p01.x, n1 = (float)p01.y, n2 = (float)p2x.x;

    const float* Cb = P.C[b];
    const float sg = P.sigma[b];
    float o0 = fmaf(Cb[0], r, fmaf(Cb[1], g, fmaf(Cb[2],  bl, Cb[3])));
    float o1 = fmaf(Cb[4], r, fmaf(Cb[5], g, fmaf(Cb[6],  bl, Cb[7])));
    float o2 = fmaf(Cb[8], r, fmaf(Cb[9], g, fmaf(Cb[10], bl, Cb[11])));
    o0 = fmaf(n0, sg, o0);
    o1 = fmaf(n1, sg, o1);
    o2 = fmaf(n2, sg, o2);

    float fxn = ((float)x + 0.5f) * 0.015625f;
    float fyn = ((float)y + 0.5f) * 0.015625f;
    float fzn = ((float)z + 0.5f) * 0.015625f;
    bool keep = (fabsf(fxn - P.cx[b]) >= 0.25f) ||
                (fabsf(fyn - P.cy[b]) >= 0.25f) ||
                (fabsf(fzn - P.cz[b]) >= 0.25f);
    float mk = keep ? 1.0f : 0.0f;

    size_t ob = (size_t)b * 786432 + (size_t)vox;
    out[ob]           = o0 * mk;
    out[ob + 262144]  = o1 * mk;
    out[ob + 524288]  = o2 * mk;
}

// ---------------------------------------------------------------------------
// Fallback path A (proven r9, 63.5us): repack only, RNG in main kernel.
// ---------------------------------------------------------------------------
__global__ __launch_bounds__(256) void repack_kernel(const float* __restrict__ in,
                                                     float4* __restrict__ ws4) {
    const int t = blockIdx.x * 256 + threadIdx.x;
    const int b = t >> 18;
    const int vox = t & 262143;
    const float* p = in + (size_t)b * 786432 + vox;
    float4 q;
    q.x = p[0];
    q.y = p[262144];
    q.z = p[524288];
    q.w = 0.0f;
    ws4[t] = q;
}

__global__ __launch_bounds__(256, 4) void aug_kernel4(const float4* __restrict__ ws4,
                                                      float* __restrict__ out,
                                                      AugParams P) {
    const int bid = blockIdx.x;
    const int b = bid >> 10;
    const int vox = ((bid & 1023) << 8) | threadIdx.x;
    const int x = vox & 63;
    const int y = (vox >> 6) & 63;
    const int z = vox >> 12;

    const float* Gb = P.G[b];
    const float hx = (float)x - 31.5f;
    const float hy = (float)y - 31.5f;
    const float hz = (float)z - 31.5f;
    float sx = Gb[0] * hx + Gb[1] * hy + Gb[2]  * hz + Gb[3]  + 31.5f;
    float sy = Gb[4] * hx + Gb[5] * hy + Gb[6]  * hz + Gb[7]  + 31.5f;
    float sz = Gb[8] * hx + Gb[9] * hy + Gb[10] * hz + Gb[11] + 31.5f;

    float fx = floorf(sx), fy = floorf(sy), fz = floorf(sz);
    float wx = sx - fx, wy = sy - fy, wz = sz - fz;
    int ix = (int)fx, iy = (int)fy, iz = (int)fz;

    float xw0 = ((unsigned)ix       < 64u) ? 1.0f - wx : 0.0f;
    float xw1 = ((unsigned)(ix + 1) < 64u) ? wx        : 0.0f;
    float yw0 = ((unsigned)iy       < 64u) ? 1.0f - wy : 0.0f;
    float yw1 = ((unsigned)(iy + 1) < 64u) ? wy        : 0.0f;
    float zw0 = ((unsigned)iz       < 64u) ? 1.0f - wz : 0.0f;
    float zw1 = ((unsigned)(iz + 1) < 64u) ? wz        : 0.0f;

    int xc0 = min(max(ix, 0), 63),       xc1 = min(max(ix + 1, 0), 63);
    int yo0 = min(max(iy, 0), 63) << 6,  yo1 = min(max(iy + 1, 0), 63) << 6;
    int zo0 = min(max(iz, 0), 63) << 12, zo1 = min(max(iz + 1, 0), 63) << 12;

    float w00 = zw0 * yw0, w01 = zw0 * yw1, w10 = zw1 * yw0, w11 = zw1 * yw1;
    int   o00 = zo0 + yo0, o01 = zo0 + yo1, o10 = zo1 + yo0, o11 = zo1 + yo1;

    const float4* __restrict__ w4 = ws4 + (size_t)b * 262144;
    float r = 0.0f, g = 0.0f, bl = 0.0f;
#define CORNER4(W, O) { \
    float4 qa = w4[(O) + xc0]; float4 qb = w4[(O) + xc1]; \
    const float wg0 = (W) * xw0, wg1 = (W) * xw1; \
    r  = fmaf(qa.x, wg0, r);  r  = fmaf(qb.x, wg1, r);  \
    g  = fmaf(qa.y, wg0, g);  g  = fmaf(qb.y, wg1, g);  \
    bl = fmaf(qa.z, wg0, bl); bl = fmaf(qb.z, wg1, bl); }
    CORNER4(w00, o00) CORNER4(w01, o01) CORNER4(w10, o10) CORNER4(w11, o11)
#undef CORNER4

    const uint32_t l0 = (uint32_t)b * 786432u + (uint32_t)vox;
    float n0, n1, n2;
    noise3(P.nk0, P.nk1, l0, n0, n1, n2);

    const float* Cb = P.C[b];
    const float sg = P.sigma[b];
    float o0 = fmaf(Cb[0], r, fmaf(Cb[1], g, fmaf(Cb[2],  bl, Cb[3])));
    float o1 = fmaf(Cb[4], r, fmaf(Cb[5], g, fmaf(Cb[6],  bl, Cb[7])));
    float o2 = fmaf(Cb[8], r, fmaf(Cb[9], g, fmaf(Cb[10], bl, Cb[11])));
    o0 = fmaf(n0, sg, o0);
    o1 = fmaf(n1, sg, o1);
    o2 = fmaf(n2, sg, o2);

    float fxn = ((float)x + 0.5f) * 0.015625f;
    float fyn = ((float)y + 0.5f) * 0.015625f;
    float fzn = ((float)z + 0.5f) * 0.015625f;
    bool keep = (fabsf(fxn - P.cx[b]) >= 0.25f) ||
                (fabsf(fyn - P.cy[b]) >= 0.25f) ||
                (fabsf(fzn - P.cz[b]) >= 0.25f);
    float mk = keep ? 1.0f : 0.0f;

    size_t ob = (size_t)b * 786432 + (size_t)vox;
    out[ob]           = o0 * mk;
    out[ob + 262144]  = o1 * mk;
    out[ob + 524288]  = o2 * mk;
}

// ---------------------------------------------------------------------------
// Fallback path B (r4, 94.7us): planar input, no workspace.
// ---------------------------------------------------------------------------
__global__ __launch_bounds__(256, 4) void aug_kernel_planar(const float* __restrict__ in,
                                                            float* __restrict__ out,
                                                            AugParams P) {
    const int bid = blockIdx.x;
    const int b = bid >> 10;
    const int vox = ((bid & 1023) << 8) | threadIdx.x;
    const int x = vox & 63;
    const int y = (vox >> 6) & 63;
    const int z = vox >> 12;

    const float* Gb = P.G[b];
    const float hx = (float)x - 31.5f;
    const float hy = (float)y - 31.5f;
    const float hz = (float)z - 31.5f;
    float sx = Gb[0] * hx + Gb[1] * hy + Gb[2]  * hz + Gb[3]  + 31.5f;
    float sy = Gb[4] * hx + Gb[5] * hy + Gb[6]  * hz + Gb[7]  + 31.5f;
    float sz = Gb[8] * hx + Gb[9] * hy + Gb[10] * hz + Gb[11] + 31.5f;

    float fx = floorf(sx), fy = floorf(sy), fz = floorf(sz);
    float wx = sx - fx, wy = sy - fy, wz = sz - fz;
    int ix = (int)fx, iy = (int)fy, iz = (int)fz;

    float xw0 = ((unsigned)ix       < 64u) ? 1.0f - wx : 0.0f;
    float xw1 = ((unsigned)(ix + 1) < 64u) ? wx        : 0.0f;
    float yw0 = ((unsigned)iy       < 64u) ? 1.0f - wy : 0.0f;
    float yw1 = ((unsigned)(iy + 1) < 64u) ? wy        : 0.0f;
    float zw0 = ((unsigned)iz       < 64u) ? 1.0f - wz : 0.0f;
    float zw1 = ((unsigned)(iz + 1) < 64u) ? wz        : 0.0f;

    int xc0 = min(max(ix, 0), 63),       xc1 = min(max(ix + 1, 0), 63);
    int yo0 = min(max(iy, 0), 63) << 6,  yo1 = min(max(iy + 1, 0), 63) << 6;
    int zo0 = min(max(iz, 0), 63) << 12, zo1 = min(max(iz + 1, 0), 63) << 12;

    float w00 = zw0 * yw0, w01 = zw0 * yw1, w10 = zw1 * yw0, w11 = zw1 * yw1;
    int   o00 = zo0 + yo0, o01 = zo0 + yo1, o10 = zo1 + yo0, o11 = zo1 + yo1;

    const float* __restrict__ imb = in + (size_t)b * 786432;
    float r = 0.0f, g = 0.0f, bl = 0.0f;
#define CORNER(W, O) { \
    const int off0 = (O) + xc0, off1 = (O) + xc1; \
    const float wg0 = (W) * xw0, wg1 = (W) * xw1; \
    r  = fmaf(imb[off0],          wg0, r);  r  = fmaf(imb[off1],          wg1, r);  \
    g  = fmaf(imb[262144 + off0], wg0, g);  g  = fmaf(imb[262144 + off1], wg1, g);  \
    bl = fmaf(imb[524288 + off0], wg0, bl); bl = fmaf(imb[524288 + off1], wg1, bl); }
    CORNER(w00, o00) CORNER(w01, o01) CORNER(w10, o10) CORNER(w11, o11)
#undef CORNER

    const uint32_t l0 = (uint32_t)b * 786432u + (uint32_t)vox;
    float n0, n1, n2;
    noise3(P.nk0, P.nk1, l0, n0, n1, n2);

    const float* Cb = P.C[b];
    const float sg = P.sigma[b];
    float o0 = fmaf(Cb[0], r, fmaf(Cb[1], g, fmaf(Cb[2],  bl, Cb[3])));
    float o1 = fmaf(Cb[4], r, fmaf(Cb[5], g, fmaf(Cb[6],  bl, Cb[7])));
    float o2 = fmaf(Cb[8], r, fmaf(Cb[9], g, fmaf(Cb[10], bl, Cb[11])));
    o0 = fmaf(n0, sg, o0);
    o1 = fmaf(n1, sg, o1);
    o2 = fmaf(n2, sg, o2);

    float fxn = ((float)x + 0.5f) * 0.015625f;
    float fyn = ((float)y + 0.5f) * 0.015625f;
    float fzn = ((float)z + 0.5f) * 0.015625f;
    bool keep = (fabsf(fxn - P.cx[b]) >= 0.25f) ||
                (fabsf(fyn - P.cy[b]) >= 0.25f) ||
                (fabsf(fzn - P.cz[b]) >= 0.25f);
    float mk = keep ? 1.0f : 0.0f;

    size_t ob = (size_t)b * 786432 + (size_t)vox;
    out[ob]           = o0 * mk;
    out[ob + 262144]  = o1 * mk;
    out[ob + 524288]  = o2 * mk;
}

// ---------------------------------------------------------------------------
extern "C" void kernel_launch(void* const* d_in, const int* in_sizes, int n_in,
                              void* d_out, int out_size, void* d_ws, size_t ws_size,
                              hipStream_t stream) {
    const float* in = (const float*)d_in[0];
    float* out = (float*)d_out;

    AugParams P;
    build_params(P);  // pure host math, deterministic, graph-capture safe

    const size_t N = (size_t)16 * 262144;
    const size_t need_rgba  = N * sizeof(float4);          // 64 MiB
    const size_t need_noise = N * sizeof(uint2);           // 32 MiB
    if (ws_size >= need_rgba + need_noise) {
        float4* ws4 = (float4*)d_ws;
        uint2*  nzb = (uint2*)((char*)d_ws + need_rgba);
        repack_noise_kernel<<<dim3(16384), dim3(256), 0, stream>>>(in, ws4, nzb, P.nk0, P.nk1);
        aug_kernel4n<<<dim3(16384), dim3(256), 0, stream>>>(ws4, nzb, out, P);
    } else if (ws_size >= need_rgba) {
        float4* ws4 = (float4*)d_ws;
        repack_kernel<<<dim3(16384), dim3(256), 0, stream>>>(in, ws4);
        aug_kernel4<<<dim3(16384), dim3(256), 0, stream>>>(ws4, out, P);
    } else {
        aug_kernel_planar<<<dim3(16384), dim3(256), 0, stream>>>(in, out, P);
    }
}

// Round 12
// 63.306 us; speedup vs baseline: 1.0990x; 1.0990x over previous
//
#include <hip/hip_runtime.h>
#include <cstring>
#include <cstdint>
#include <cmath>

// ---------------------------------------------------------------------------
// Threefry-2x32 (20 rounds) — exact JAX PRNG
// ---------------------------------------------------------------------------
__host__ __device__ static inline uint32_t rotl32(uint32_t v, int r) {
    return __builtin_rotateleft32(v, (unsigned)r);
}

__host__ __device__ static inline void tf2x32(uint32_t k0, uint32_t k1,
                                              uint32_t& x0, uint32_t& x1) {
    uint32_t ks2 = k0 ^ k1 ^ 0x1BD11BDAu;
    x0 += k0; x1 += k1;
#define TFR(r) { x0 += x1; x1 = rotl32(x1, r); x1 ^= x0; }
    TFR(13) TFR(15) TFR(26) TFR(6)
    x0 += k1;  x1 += ks2 + 1u;
    TFR(17) TFR(29) TFR(16) TFR(24)
    x0 += ks2; x1 += k0 + 2u;
    TFR(13) TFR(15) TFR(26) TFR(6)
    x0 += k0;  x1 += k1 + 3u;
    TFR(17) TFR(29) TFR(16) TFR(24)
    x0 += k1;  x1 += ks2 + 4u;
    TFR(13) TFR(15) TFR(26) TFR(6)
    x0 += ks2; x1 += k0 + 5u;
#undef TFR
}

// Partitionable-mode 32-bit random bits for flat index i: counter (0,i); out0^out1
__host__ __device__ static inline uint32_t pbits(uint32_t k0, uint32_t k1, uint32_t i) {
    uint32_t a = 0u, b = i;
    tf2x32(k0, k1, a, b);
    return a ^ b;
}

// bits -> uniform [0,1) exactly as jax
__host__ __device__ static inline float bits_to_u01(uint32_t bits) {
    uint32_t u = (bits >> 9) | 0x3f800000u;
    float f; memcpy(&f, &u, 4);
    return f - 1.0f;
}

// XLA ErfInv (Giles 2010, float32) — PRECISE version (host-side params only)
__host__ static inline float erfinv_f(float x) {
    float w = -log1pf(-x * x);
    float p;
    if (w < 5.0f) {
        w = w - 2.5f;
        p = 2.81022636e-08f;
        p = fmaf(p, w, 3.43273939e-07f);
        p = fmaf(p, w, -3.5233877e-06f);
        p = fmaf(p, w, -4.39150654e-06f);
        p = fmaf(p, w, 0.00021858087f);
        p = fmaf(p, w, -0.00125372503f);
        p = fmaf(p, w, -0.00417768164f);
        p = fmaf(p, w, 0.246640727f);
        p = fmaf(p, w, 1.50140941f);
    } else {
        w = sqrtf(w) - 3.0f;
        p = -0.000200214257f;
        p = fmaf(p, w, 0.000100950558f);
        p = fmaf(p, w, 0.00134934322f);
        p = fmaf(p, w, -0.00367342844f);
        p = fmaf(p, w, 0.00573950773f);
        p = fmaf(p, w, -0.0076224613f);
        p = fmaf(p, w, 0.00943887047f);
        p = fmaf(p, w, 1.00167406f);
        p = fmaf(p, w, 2.83297682f);
    }
    return p * x;
}

__host__ static inline float normal_from_bits(uint32_t bits) {
    const float LO = -0.999999940395355224609375f;  // -1 + 2^-24
    float u01 = bits_to_u01(bits);
    float u = u01 * 2.0f + LO;
    u = (u > LO) ? u : LO;
    return 1.4142135623730951f * erfinv_f(u);
}

// ---------------------------------------------------------------------------
// Device-fast normal (validated rounds 3-11: absmax stable 0.0625)
// ---------------------------------------------------------------------------
__device__ __forceinline__ float normal_fast(uint32_t bits) {
    const float LO = -0.999999940395355224609375f;
    uint32_t u = (bits >> 9) | 0x3f800000u;
    float x = fmaf(__uint_as_float(u) - 1.0f, 2.0f, LO);
    x = fmaxf(x, LO);
    float t = fmaf(x, -x, 1.0f);            // 1 - x^2, single rounding
    float lg = __log2f(t);                   // v_log_f32
    float p;
    if (__builtin_expect(lg > -7.2134752044448170f, 1)) {   // w < 5
        float w = fmaf(lg, -0.6931471805599453f, -2.5f);
        p = 2.81022636e-08f;
        p = fmaf(p, w, 3.43273939e-07f);
        p = fmaf(p, w, -3.5233877e-06f);
        p = fmaf(p, w, -4.39150654e-06f);
        p = fmaf(p, w, 0.00021858087f);
        p = fmaf(p, w, -0.00125372503f);
        p = fmaf(p, w, -0.00417768164f);
        p = fmaf(p, w, 0.246640727f);
        p = fmaf(p, w, 1.50140941f);
    } else {
        float w = sqrtf(lg * -0.6931471805599453f) - 3.0f;
        p = -0.000200214257f;
        p = fmaf(p, w, 0.000100950558f);
        p = fmaf(p, w, 0.00134934322f);
        p = fmaf(p, w, -0.00367342844f);
        p = fmaf(p, w, 0.00573950773f);
        p = fmaf(p, w, -0.0076224613f);
        p = fmaf(p, w, 0.00943887047f);
        p = fmaf(p, w, 1.00167406f);
        p = fmaf(p, w, 2.83297682f);
    }
    return 1.4142135623730951f * p * x;
}

// Three interleaved threefry chains (same key, counters l, l+256K, l+512K).
__device__ __forceinline__ void noise3(uint32_t k0, uint32_t k1, uint32_t l,
                                       float& n0, float& n1, float& n2) {
    const uint32_t ks2 = k0 ^ k1 ^ 0x1BD11BDAu;
    uint32_t a0 = k0, b0 = l + k1;
    uint32_t a1 = k0, b1 = (l + 262144u) + k1;
    uint32_t a2 = k0, b2 = (l + 524288u) + k1;
#define R3(r)      { a0 += b0; b0 = rotl32(b0, r); b0 ^= a0; \
                     a1 += b1; b1 = rotl32(b1, r); b1 ^= a1; \
                     a2 += b2; b2 = rotl32(b2, r); b2 ^= a2; }
#define INJ(ka,kb) { a0 += (ka); b0 += (kb); a1 += (ka); b1 += (kb); a2 += (ka); b2 += (kb); }
    R3(13) R3(15) R3(26) R3(6)  INJ(k1,  ks2 + 1u)
    R3(17) R3(29) R3(16) R3(24) INJ(ks2, k0  + 2u)
    R3(13) R3(15) R3(26) R3(6)  INJ(k0,  k1  + 3u)
    R3(17) R3(29) R3(16) R3(24) INJ(k1,  ks2 + 4u)
    R3(13) R3(15) R3(26) R3(6)  INJ(ks2, k0  + 5u)
#undef R3
#undef INJ
    n0 = normal_fast(a0 ^ b0);
    n1 = normal_fast(a1 ^ b1);
    n2 = normal_fast(a2 ^ b2);
}

// ---------------------------------------------------------------------------
// Host-side float32 4x4 matrix helpers (exact reference mirror)
// ---------------------------------------------------------------------------
struct M4 { float m[4][4]; };

static M4 m4_eye() {
    M4 r;
    for (int i = 0; i < 4; ++i)
        for (int j = 0; j < 4; ++j) r.m[i][j] = (i == j) ? 1.0f : 0.0f;
    return r;
}
static M4 m4_mul(const M4& A, const M4& B) {
    M4 r;
    for (int i = 0; i < 4; ++i)
        for (int j = 0; j < 4; ++j) {
            float s = 0.0f;
            for (int k = 0; k < 4; ++k) s += A.m[i][k] * B.m[k][j];
            r.m[i][j] = s;
        }
    return r;
}
static M4 m4_scale(float sx, float sy, float sz) {
    M4 r = m4_eye(); r.m[0][0] = sx; r.m[1][1] = sy; r.m[2][2] = sz; return r;
}
static M4 m4_trans(float tx, float ty, float tz) {
    M4 r = m4_eye(); r.m[0][3] = tx; r.m[1][3] = ty; r.m[2][3] = tz; return r;
}
static M4 m4_rotz(float th) {
    float c = cosf(th), s = sinf(th);
    M4 r = m4_eye();
    r.m[0][0] = c; r.m[0][1] = -s; r.m[1][0] = s; r.m[1][1] = c;
    return r;
}
static M4 m4_rotluma(float th) {
    const float a  = 0.57735026918962576f;
    const float a2 = 1.0f / 3.0f;
    float c = cosf(th), s = sinf(th), cc = 1.0f - c;
    float d  = a2 * cc + c;
    float mm = a2 * cc - a * s;
    float pp = a2 * cc + a * s;
    M4 r = m4_eye();
    r.m[0][0] = d;  r.m[0][1] = mm; r.m[0][2] = pp;
    r.m[1][0] = pp; r.m[1][1] = d;  r.m[1][2] = mm;
    r.m[2][0] = mm; r.m[2][1] = pp; r.m[2][2] = d;
    return r;
}

// ---------------------------------------------------------------------------
struct AugParams {
    float G[16][12];
    float C[16][12];
    float sigma[16];
    float cx[16], cy[16], cz[16];
    uint32_t nk0, nk1;
};

static void build_params(AugParams& P) {
    uint32_t sk0[24], sk1[24];
    for (int j = 0; j < 24; ++j) {
        uint32_t a = 0u, b = (uint32_t)j;
        tf2x32(0u, 42u, a, b);
        sk0[j] = a; sk1[j] = b;
    }

    float u_xf[16], u_r90[16], u_ti[48], n_sc[16], u_r1[16], n_an[16], u_r2[16];
    float n_tf[48], n_br[16], n_ct[16], u_lf[16], u_hue[16], n_sat[16], n_sig[16], u_cut[48];

    auto fill_u = [&](int j, int n, float* o) {
        for (int i = 0; i < n; ++i) o[i] = bits_to_u01(pbits(sk0[j], sk1[j], (uint32_t)i));
    };
    auto fill_n = [&](int j, int n, float* o) {
        for (int i = 0; i < n; ++i) o[i] = normal_from_bits(pbits(sk0[j], sk1[j], (uint32_t)i));
    };

    fill_u(0, 16, u_xf);  fill_u(1, 16, u_r90);  fill_u(2, 48, u_ti);
    fill_n(3, 16, n_sc);  fill_u(4, 16, u_r1);   fill_n(5, 16, n_an);
    fill_u(6, 16, u_r2);  fill_n(7, 48, n_tf);   fill_n(8, 16, n_br);
    fill_n(9, 16, n_ct);  fill_u(10, 16, u_lf);  fill_u(11, 16, u_hue);
    fill_n(12, 16, n_sat); fill_n(13, 16, n_sig); fill_u(15, 48, u_cut);
    P.nk0 = sk0[14]; P.nk1 = sk1[14];

    const float PI_F = 3.14159265358979323846f;
    const float HPI_F = 1.5707963267948966f;

    for (int b = 0; b < 16; ++b) {
        M4 G = m4_eye();
        float i1 = floorf(u_xf[b] * 2.0f);
        G = m4_mul(G, m4_scale(1.0f - 2.0f * i1, 1.0f, 1.0f));
        float i2 = floorf(u_r90[b] * 4.0f);
        G = m4_mul(G, m4_rotz(-HPI_F * i2));
        float t0 = (u_ti[3 * b + 0] * 2.0f - 1.0f) * 0.125f;
        float t1 = (u_ti[3 * b + 1] * 2.0f - 1.0f) * 0.125f;
        float t2 = (u_ti[3 * b + 2] * 2.0f - 1.0f) * 0.125f;
        G = m4_mul(G, m4_trans(-rintf(t0 * 64.0f), -rintf(t1 * 64.0f), -rintf(t2 * 64.0f)));
        float s = exp2f(n_sc[b] * 0.2f);
        G = m4_mul(G, m4_scale(1.0f / s, 1.0f / s, 1.0f / s));
        float th1 = (u_r1[b] * 2.0f - 1.0f) * PI_F;
        G = m4_mul(G, m4_rotz(-th1));
        float s2 = exp2f(n_an[b] * 0.2f);
        G = m4_mul(G, m4_scale(1.0f / s2, s2, 1.0f));
        float th2 = (u_r2[b] * 2.0f - 1.0f) * PI_F;
        G = m4_mul(G, m4_rotz(-th2));
        float f0 = n_tf[3 * b + 0] * 0.125f;
        float f1 = n_tf[3 * b + 1] * 0.125f;
        float f2 = n_tf[3 * b + 2] * 0.125f;
        G = m4_mul(G, m4_trans(-f0 * 64.0f, -f1 * 64.0f, -f2 * 64.0f));

        M4 C = m4_eye();
        float br = n_br[b] * 0.2f;
        C = m4_mul(m4_trans(br, br, br), C);
        float ct = exp2f(n_ct[b] * 0.5f);
        C = m4_mul(m4_scale(ct, ct, ct), C);
        const float va = 0.57735026918962576f;
        float v4[4] = { va, va, va, 0.0f };
        float ilf = floorf(u_lf[b] * 2.0f);
        M4 L;
        for (int r = 0; r < 4; ++r)
            for (int c = 0; c < 4; ++c)
                L.m[r][c] = ((r == c) ? 1.0f : 0.0f) - 2.0f * (v4[r] * v4[c]) * ilf;
        C = m4_mul(L, C);
        float thh = (u_hue[b] * 2.0f - 1.0f) * PI_F;
        C = m4_mul(m4_rotluma(thh), C);
        float ss = exp2f(n_sat[b] * 1.0f);
        M4 S;
        for (int r = 0; r < 4; ++r)
            for (int c = 0; c < 4; ++c) {
                float vv = v4[r] * v4[c];
                S.m[r][c] = vv + (((r == c) ? 1.0f : 0.0f) - vv) * ss;
            }
        C = m4_mul(S, C);

        P.sigma[b] = fabsf(n_sig[b]) * 0.1f;
        P.cx[b] = u_cut[3 * b + 0];
        P.cy[b] = u_cut[3 * b + 1];
        P.cz[b] = u_cut[3 * b + 2];
        for (int r = 0; r < 3; ++r)
            for (int c = 0; c < 4; ++c) {
                P.G[b][r * 4 + c] = G.m[r][c];
                P.C[b][r * 4 + c] = C.m[r][c];
            }
    }
}

// ---------------------------------------------------------------------------
// Kernel 1: planar [16][3][64^3] -> interleaved RGBA float4 (r9, proven).
// ---------------------------------------------------------------------------
__global__ __launch_bounds__(256) void repack_kernel(const float* __restrict__ in,
                                                     float4* __restrict__ ws4) {
    const int t = blockIdx.x * 256 + threadIdx.x;
    const int b = t >> 18;
    const int vox = t & 262143;
    const float* p = in + (size_t)b * 786432 + vox;
    float4 q;
    q.x = p[0];
    q.y = p[262144];
    q.z = p[524288];
    q.w = 0.0f;
    ws4[t] = q;
}

// ---------------------------------------------------------------------------
// Kernel 2: main fused augment (r9 structure) with ONE change: the 8 corner
// loads are issued first and pinned by a sched_barrier that allows ALL
// non-VMEM instructions to cross (mask: ALU|VALU|SALU|MFMA|VMEM_WRITE|DS* =
// 0x3CF) — so the RNG VALU schedules freely UNDER the loads, but the
// scheduler cannot re-sink the loads to their uses (the r5 failure mode).
// ---------------------------------------------------------------------------
__global__ __launch_bounds__(256, 4) void aug_kernel4(const float4* __restrict__ ws4,
                                                      float* __restrict__ out,
                                                      AugParams P) {
    const int bid = blockIdx.x;
    const int b = bid >> 10;
    const int vox = ((bid & 1023) << 8) | threadIdx.x;
    const int x = vox & 63;
    const int y = (vox >> 6) & 63;
    const int z = vox >> 12;

    const float* Gb = P.G[b];
    const float hx = (float)x - 31.5f;
    const float hy = (float)y - 31.5f;
    const float hz = (float)z - 31.5f;
    float sx = Gb[0] * hx + Gb[1] * hy + Gb[2]  * hz + Gb[3]  + 31.5f;
    float sy = Gb[4] * hx + Gb[5] * hy + Gb[6]  * hz + Gb[7]  + 31.5f;
    float sz = Gb[8] * hx + Gb[9] * hy + Gb[10] * hz + Gb[11] + 31.5f;

    float fx = floorf(sx), fy = floorf(sy), fz = floorf(sz);
    float wx = sx - fx, wy = sy - fy, wz = sz - fz;
    int ix = (int)fx, iy = (int)fy, iz = (int)fz;

    float xw0 = ((unsigned)ix       < 64u) ? 1.0f - wx : 0.0f;
    float xw1 = ((unsigned)(ix + 1) < 64u) ? wx        : 0.0f;
    float yw0 = ((unsigned)iy       < 64u) ? 1.0f - wy : 0.0f;
    float yw1 = ((unsigned)(iy + 1) < 64u) ? wy        : 0.0f;
    float zw0 = ((unsigned)iz       < 64u) ? 1.0f - wz : 0.0f;
    float zw1 = ((unsigned)(iz + 1) < 64u) ? wz        : 0.0f;

    int xc0 = min(max(ix, 0), 63),       xc1 = min(max(ix + 1, 0), 63);
    int yo0 = min(max(iy, 0), 63) << 6,  yo1 = min(max(iy + 1, 0), 63) << 6;
    int zo0 = min(max(iz, 0), 63) << 12, zo1 = min(max(iz + 1, 0), 63) << 12;

    int o00 = zo0 + yo0, o01 = zo0 + yo1, o10 = zo1 + yo0, o11 = zo1 + yo1;

    const float4* __restrict__ w4 = ws4 + (size_t)b * 262144;

    // ---- issue all 8 gather loads into independent temps ----
    float4 qa00 = w4[o00 + xc0], qb00 = w4[o00 + xc1];
    float4 qa01 = w4[o01 + xc0], qb01 = w4[o01 + xc1];
    float4 qa10 = w4[o10 + xc0], qb10 = w4[o10 + xc1];
    float4 qa11 = w4[o11 + xc0], qb11 = w4[o11 + xc1];

    // Pin VMEM here (loads may not sink below); ALL arithmetic may cross.
    // mask = ALU|VALU|SALU|MFMA|VMEM_WRITE|DS|DS_READ|DS_WRITE = 0x3CF
    __builtin_amdgcn_sched_barrier(0x3CF);

    // ---- RNG: schedules under the in-flight loads ----
    const uint32_t l0 = (uint32_t)b * 786432u + (uint32_t)vox;
    float n0, n1, n2;
    noise3(P.nk0, P.nk1, l0, n0, n1, n2);

    // ---- weighted accumulate ----
    float w00 = zw0 * yw0, w01 = zw0 * yw1, w10 = zw1 * yw0, w11 = zw1 * yw1;
    float wa00 = w00 * xw0, wb00 = w00 * xw1;
    float wa01 = w01 * xw0, wb01 = w01 * xw1;
    float wa10 = w10 * xw0, wb10 = w10 * xw1;
    float wa11 = w11 * xw0, wb11 = w11 * xw1;

    float r = qa00.x * wa00;  r = fmaf(qb00.x, wb00, r);
    r = fmaf(qa01.x, wa01, r); r = fmaf(qb01.x, wb01, r);
    r = fmaf(qa10.x, wa10, r); r = fmaf(qb10.x, wb10, r);
    r = fmaf(qa11.x, wa11, r); r = fmaf(qb11.x, wb11, r);

    float g = qa00.y * wa00;  g = fmaf(qb00.y, wb00, g);
    g = fmaf(qa01.y, wa01, g); g = fmaf(qb01.y, wb01, g);
    g = fmaf(qa10.y, wa10, g); g = fmaf(qb10.y, wb10, g);
    g = fmaf(qa11.y, wa11, g); g = fmaf(qb11.y, wb11, g);

    float bl = qa00.z * wa00;  bl = fmaf(qb00.z, wb00, bl);
    bl = fmaf(qa01.z, wa01, bl); bl = fmaf(qb01.z, wb01, bl);
    bl = fmaf(qa10.z, wa10, bl); bl = fmaf(qb10.z, wb10, bl);
    bl = fmaf(qa11.z, wa11, bl); bl = fmaf(qb11.z, wb11, bl);

    const float* Cb = P.C[b];
    const float sg = P.sigma[b];
    float o0 = fmaf(Cb[0], r, fmaf(Cb[1], g, fmaf(Cb[2],  bl, Cb[3])));
    float o1 = fmaf(Cb[4], r, fmaf(Cb[5], g, fmaf(Cb[6],  bl, Cb[7])));
    float o2 = fmaf(Cb[8], r, fmaf(Cb[9], g, fmaf(Cb[10], bl, Cb[11])));
    o0 = fmaf(n0, sg, o0);
    o1 = fmaf(n1, sg, o1);
    o2 = fmaf(n2, sg, o2);

    float fxn = ((float)x + 0.5f) * 0.015625f;
    float fyn = ((float)y + 0.5f) * 0.015625f;
    float fzn = ((float)z + 0.5f) * 0.015625f;
    bool keep = (fabsf(fxn - P.cx[b]) >= 0.25f) ||
                (fabsf(fyn - P.cy[b]) >= 0.25f) ||
                (fabsf(fzn - P.cz[b]) >= 0.25f);
    float mk = keep ? 1.0f : 0.0f;

    size_t ob = (size_t)b * 786432 + (size_t)vox;
    out[ob]           = o0 * mk;
    out[ob + 262144]  = o1 * mk;
    out[ob + 524288]  = o2 * mk;
}

// ---------------------------------------------------------------------------
// Fallback (r4, 94.7us): planar input, no workspace.
// ---------------------------------------------------------------------------
__global__ __launch_bounds__(256, 4) void aug_kernel_planar(const float* __restrict__ in,
                                                            float* __restrict__ out,
                                                            AugParams P) {
    const int bid = blockIdx.x;
    const int b = bid >> 10;
    const int vox = ((bid & 1023) << 8) | threadIdx.x;
    const int x = vox & 63;
    const int y = (vox >> 6) & 63;
    const int z = vox >> 12;

    const float* Gb = P.G[b];
    const float hx = (float)x - 31.5f;
    const float hy = (float)y - 31.5f;
    const float hz = (float)z - 31.5f;
    float sx = Gb[0] * hx + Gb[1] * hy + Gb[2]  * hz + Gb[3]  + 31.5f;
    float sy = Gb[4] * hx + Gb[5] * hy + Gb[6]  * hz + Gb[7]  + 31.5f;
    float sz = Gb[8] * hx + Gb[9] * hy + Gb[10] * hz + Gb[11] + 31.5f;

    float fx = floorf(sx), fy = floorf(sy), fz = floorf(sz);
    float wx = sx - fx, wy = sy - fy, wz = sz - fz;
    int ix = (int)fx, iy = (int)fy, iz = (int)fz;

    float xw0 = ((unsigned)ix       < 64u) ? 1.0f - wx : 0.0f;
    float xw1 = ((unsigned)(ix + 1) < 64u) ? wx        : 0.0f;
    float yw0 = ((unsigned)iy       < 64u) ? 1.0f - wy : 0.0f;
    float yw1 = ((unsigned)(iy + 1) < 64u) ? wy        : 0.0f;
    float zw0 = ((unsigned)iz       < 64u) ? 1.0f - wz : 0.0f;
    float zw1 = ((unsigned)(iz + 1) < 64u) ? wz        : 0.0f;

    int xc0 = min(max(ix, 0), 63),       xc1 = min(max(ix + 1, 0), 63);
    int yo0 = min(max(iy, 0), 63) << 6,  yo1 = min(max(iy + 1, 0), 63) << 6;
    int zo0 = min(max(iz, 0), 63) << 12, zo1 = min(max(iz + 1, 0), 63) << 12;

    float w00 = zw0 * yw0, w01 = zw0 * yw1, w10 = zw1 * yw0, w11 = zw1 * yw1;
    int   o00 = zo0 + yo0, o01 = zo0 + yo1, o10 = zo1 + yo0, o11 = zo1 + yo1;

    const float* __restrict__ imb = in + (size_t)b * 786432;
    float r = 0.0f, g = 0.0f, bl = 0.0f;
#define CORNER(W, O) { \
    const int off0 = (O) + xc0, off1 = (O) + xc1; \
    const float wg0 = (W) * xw0, wg1 = (W) * xw1; \
    r  = fmaf(imb[off0],          wg0, r);  r  = fmaf(imb[off1],          wg1, r);  \
    g  = fmaf(imb[262144 + off0], wg0, g);  g  = fmaf(imb[262144 + off1], wg1, g);  \
    bl = fmaf(imb[524288 + off0], wg0, bl); bl = fmaf(imb[524288 + off1], wg1, bl); }
    CORNER(w00, o00) CORNER(w01, o01) CORNER(w10, o10) CORNER(w11, o11)
#undef CORNER

    const uint32_t l0 = (uint32_t)b * 786432u + (uint32_t)vox;
    float n0, n1, n2;
    noise3(P.nk0, P.nk1, l0, n0, n1, n2);

    const float* Cb = P.C[b];
    const float sg = P.sigma[b];
    float o0 = fmaf(Cb[0], r, fmaf(Cb[1], g, fmaf(Cb[2],  bl, Cb[3])));
    float o1 = fmaf(Cb[4], r, fmaf(Cb[5], g, fmaf(Cb[6],  bl, Cb[7])));
    float o2 = fmaf(Cb[8], r, fmaf(Cb[9], g, fmaf(Cb[10], bl, Cb[11])));
    o0 = fmaf(n0, sg, o0);
    o1 = fmaf(n1, sg, o1);
    o2 = fmaf(n2, sg, o2);

    float fxn = ((float)x + 0.5f) * 0.015625f;
    float fyn = ((float)y + 0.5f) * 0.015625f;
    float fzn = ((float)z + 0.5f) * 0.015625f;
    bool keep = (fabsf(fxn - P.cx[b]) >= 0.25f) ||
                (fabsf(fyn - P.cy[b]) >= 0.25f) ||
                (fabsf(fzn - P.cz[b]) >= 0.25f);
    float mk = keep ? 1.0f : 0.0f;

    size_t ob = (size_t)b * 786432 + (size_t)vox;
    out[ob]           = o0 * mk;
    out[ob + 262144]  = o1 * mk;
    out[ob + 524288]  = o2 * mk;
}

// ---------------------------------------------------------------------------
extern "C" void kernel_launch(void* const* d_in, const int* in_sizes, int n_in,
                              void* d_out, int out_size, void* d_ws, size_t ws_size,
                              hipStream_t stream) {
    const float* in = (const float*)d_in[0];
    float* out = (float*)d_out;

    AugParams P;
    build_params(P);  // pure host math, deterministic, graph-capture safe

    const size_t need_rgba = (size_t)16 * 262144 * sizeof(float4);  // 64 MiB
    if (ws_size >= need_rgba) {
        float4* ws4 = (float4*)d_ws;
        repack_kernel<<<dim3(16384), dim3(256), 0, stream>>>(in, ws4);
        aug_kernel4<<<dim3(16384), dim3(256), 0, stream>>>(ws4, out, P);
    } else {
        aug_kernel_planar<<<dim3(16384), dim3(256), 0, stream>>>(in, out, P);
    }
}